// Round 4
// baseline (787.305 us; speedup 1.0000x reference)
//
#include <hip/hip_runtime.h>
#include <float.h>

#define N_ROWS 65536
#define D_IN   128
#define DH     64
#define K_CB   2048

typedef const __attribute__((address_space(1))) void* gas_p;
typedef __attribute__((address_space(3))) void* las_p;
typedef _Float16 f16x8 __attribute__((ext_vector_type(8)));
typedef float    f32x4 __attribute__((ext_vector_type(4)));

// ---------------- K_prep: project embeddings -> epl (2-plane, swizzled) + e2 -
// 128 blocks x 16 rows. Same arithmetic as before (fp32 FMA, exact split).
__global__ __launch_bounds__(256) void k_prep(
    const float* __restrict__ emb, const float* __restrict__ W,
    const float* __restrict__ b,
    _Float16* __restrict__ epl,   // [2][K_CB][64] swizzled
    float* __restrict__ e2) {     // [K_CB]
  __shared__ __align__(16) float Wl[64 * 140];
  __shared__ __align__(16) float Zl[16 * 128];
  int tid = threadIdx.x;
  int n0 = blockIdx.x * 16;
  const size_t plane = (size_t)K_CB * 64;

#pragma unroll
  for (int i = 0; i < 8; ++i) {
    int idx4 = tid + 256 * i;
    int j = idx4 >> 5;
    int d4 = (idx4 & 31) * 4;
    *(float4*)&Wl[j * 140 + d4] = *(const float4*)(W + j * 128 + d4);
  }
#pragma unroll
  for (int i = 0; i < 2; ++i) {
    int idx4 = tid + 256 * i;
    int r = idx4 >> 5;
    int d4 = (idx4 & 31) * 4;
    *(float4*)&Zl[r * 128 + d4] = *(const float4*)(emb + (size_t)(n0 + r) * 128 + d4);
  }
  int j = tid & 63, g = tid >> 6;
  float bj = b[j];
  __syncthreads();

  float acc[4] = {0.f, 0.f, 0.f, 0.f};
  for (int d4 = 0; d4 < 128; d4 += 4) {
    float4 w4 = *(float4*)&Wl[j * 140 + d4];
#pragma unroll
    for (int i = 0; i < 4; ++i) {
      float4 z4 = *(float4*)&Zl[(g * 4 + i) * 128 + d4];
      acc[i] = fmaf(z4.x, w4.x, fmaf(z4.y, w4.y, fmaf(z4.z, w4.z, fmaf(z4.w, w4.w, acc[i]))));
    }
  }
#pragma unroll
  for (int i = 0; i < 4; ++i) {
    int n = n0 + g * 4 + i;
    float v = acc[i] + bj;
    _Float16 h = (_Float16)v;  float rm = v - (float)h;
    _Float16 m = (_Float16)rm;
    int pos = (((j >> 3) ^ (n & 7)) << 3) | (j & 7);
    size_t base = (size_t)n * 64 + pos;
    epl[base]         = h;
    epl[plane + base] = m;
    float s = v * v;
#pragma unroll
    for (int off = 32; off > 0; off >>= 1) s += __shfl_xor(s, off, 64);
    if (j == 0) e2[n] = s;
  }
}

// ---------------- K_main: fused project + MFMA score + argmin + epilogue ----
// 1024 blocks x 64 z-rows. Phase 1: project own rows (fp32, bit-identical to
// old k_project) -> Zs 2-plane LDS. Phase 2: A-frags hoisted to registers
// (invariant across K-tiles), double-buffered Es, 1 barrier/tile, OH zeroing
// streamed as NT per-tile chunks. LDS union = exactly 80 KB -> 2 blocks/CU.
__global__ __launch_bounds__(256, 2) void k_main(
    const float* __restrict__ Z, const float* __restrict__ W,
    const float* __restrict__ b,
    const _Float16* __restrict__ epl,  // [2][K_CB][64] swizzled
    const float* __restrict__ e2,      // [K_CB]
    const float* __restrict__ emb,     // [K_CB][128]
    float* __restrict__ outQ,
    float* __restrict__ outOH) {
  __shared__ __align__(16) char U[81920];
  _Float16* es0 = (_Float16*)U;              // 32 KB  (tile buf even)
  _Float16* es1 = (_Float16*)(U + 32768);    // 32 KB  (tile buf odd; phase1: Wt)
  float*    Wt  = (float*)(U + 32768);       // [128][64] f32 (phase 1 only)
  _Float16* Zs  = (_Float16*)(U + 65536);    // [2][64][64] 16 KB (phase1 -> A-read)

  int tid = threadIdx.x, lane = tid & 63, wid = tid >> 6;
  int quad = lane >> 4, l16 = lane & 15;
  int wcol = wid * 32;
  int row0 = blockIdx.x * 64;

  // ---- stage tile 0 -> es0 (region free in phase 1) ----
  for (int q = wid; q < 32; q += 4) {
    int p = q >> 4, within = (q & 15) * 1024;
    const char* g = (const char*)epl + (size_t)p * (K_CB * 128) + within + lane * 16;
    __builtin_amdgcn_global_load_lds((gas_p)g, (las_p)(U + p * 16384 + within), 16, 0, 0);
  }

  // ---- W -> Wt transpose (Wt[d][j] = W[j][d]); conflict-free LDS writes ----
#pragma unroll
  for (int i = 0; i < 8; ++i) {
    int idx4 = tid + 256 * i;
    int j = idx4 & 63, dc = idx4 >> 6;           // dc 0..31
    float4 w4 = *(const float4*)(W + (size_t)j * 128 + dc * 4);
    Wt[(dc * 4 + 0) * 64 + j] = w4.x;
    Wt[(dc * 4 + 1) * 64 + j] = w4.y;
    Wt[(dc * 4 + 2) * 64 + j] = w4.z;
    Wt[(dc * 4 + 3) * 64 + j] = w4.w;
  }

  // ---- e2 to registers (L2-hot, written by k_prep) ----
  float e2r[32];
#pragma unroll
  for (int t = 0; t < 16; ++t) {
    e2r[t * 2 + 0] = e2[t * 128 + wcol + l16];
    e2r[t * 2 + 1] = e2[t * 128 + wcol + 16 + l16];
  }

  int jj = lane;              // projection output dim
  float bj = b[jj];
  __syncthreads();            // Wt ready (also drains es0 DMA - harmless)

  // ---- projection of own 64 rows: wave g handles rows g*16..g*16+15 ----
  {
    float acc[16];
#pragma unroll
    for (int i = 0; i < 16; ++i) acc[i] = 0.f;
    const float* zbase = Z + (size_t)(row0 + wid * 16) * 128;
    for (int d4 = 0; d4 < 128; d4 += 4) {
      float w0 = Wt[(d4 + 0) * 64 + jj];
      float w1 = Wt[(d4 + 1) * 64 + jj];
      float w2 = Wt[(d4 + 2) * 64 + jj];
      float w3 = Wt[(d4 + 3) * 64 + jj];
#pragma unroll
      for (int i = 0; i < 16; ++i) {
        float4 z4 = *(const float4*)(zbase + i * 128 + d4);  // wave-uniform
        acc[i] = fmaf(z4.x, w0, fmaf(z4.y, w1, fmaf(z4.z, w2, fmaf(z4.w, w3, acc[i]))));
      }
    }
#pragma unroll
    for (int i = 0; i < 16; ++i) {
      int r = wid * 16 + i;
      float v = acc[i] + bj;
      _Float16 h = (_Float16)v;  float rm = v - (float)h;
      _Float16 m = (_Float16)rm;
      int pos = (((jj >> 3) ^ (r & 7)) << 3) | (jj & 7);
      Zs[r * 64 + pos]        = h;
      Zs[4096 + r * 64 + pos] = m;
    }
  }
  __syncthreads();            // Zs complete (Wt dead from here; es1 region free)

  // ---- A-fragments to registers, once (invariant across all K-tiles) ----
  f16x8 A[2][4][2];
#pragma unroll
  for (int step = 0; step < 2; ++step)
#pragma unroll
    for (int mt = 0; mt < 4; ++mt) {
      int tr = mt * 16 + l16;
      int cph = (step * 4 + quad) ^ (tr & 7);
      const _Float16* pa = Zs + tr * 64 + cph * 8;
      A[step][mt][0] = *(const f16x8*)pa;          // hi
      A[step][mt][1] = *(const f16x8*)(pa + 4096); // mid
    }

  float best[16]; int bidx[16];
#pragma unroll
  for (int s = 0; s < 16; ++s) { best[s] = FLT_MAX; bidx[s] = 0; }

  // ---- double-buffered tile loop: 16 tiles x 128 cols, 1 barrier/tile ----
#pragma unroll
  for (int t = 0; t < 16; ++t) {
    _Float16* esc = (t & 1) ? es1 : es0;
    if (t < 15) {           // issue next tile into the other buffer
      char* esn = (char*)((t & 1) ? es0 : es1);
      for (int q = wid; q < 32; q += 4) {
        int p = q >> 4, within = (q & 15) * 1024;
        const char* g = (const char*)epl + (size_t)p * (K_CB * 128)
                      + (size_t)(t + 1) * 16384 + within + lane * 16;
        __builtin_amdgcn_global_load_lds((gas_p)g, (las_p)(esn + p * 16384 + within), 16, 0, 0);
      }
    }
    // one_hot zero chunk for cols t*128..+127 (NT; drains at next barrier)
    {
      f32x4 zz = (f32x4){0.f, 0.f, 0.f, 0.f};
#pragma unroll
      for (int i2 = 0; i2 < 8; ++i2) {
        int idx = tid + 256 * i2;
        int r = idx >> 5, c4 = (idx & 31) * 4;
        __builtin_nontemporal_store(zz, (f32x4*)(outOH + (size_t)(row0 + r) * K_CB + t * 128 + c4));
      }
    }

    f32x4 accf[4][2];
#pragma unroll
    for (int mt = 0; mt < 4; ++mt)
#pragma unroll
      for (int nt = 0; nt < 2; ++nt) accf[mt][nt] = (f32x4){0.f, 0.f, 0.f, 0.f};

#pragma unroll
    for (int step = 0; step < 2; ++step)
#pragma unroll
      for (int nt = 0; nt < 2; ++nt) {
        int tc = wcol + nt * 16 + l16;
        int cph = (step * 4 + quad) ^ (tc & 7);
        const _Float16* pb = esc + tc * 64 + cph * 8;
        f16x8 Bh = *(const f16x8*)pb;
        f16x8 Bm = *(const f16x8*)(pb + 8192);
#pragma unroll
        for (int mt = 0; mt < 4; ++mt) {
          f32x4 c = accf[mt][nt];
          c = __builtin_amdgcn_mfma_f32_16x16x32_f16(A[step][mt][1], Bm, c, 0, 0, 0); // mm
          c = __builtin_amdgcn_mfma_f32_16x16x32_f16(A[step][mt][1], Bh, c, 0, 0, 0); // mh
          c = __builtin_amdgcn_mfma_f32_16x16x32_f16(A[step][mt][0], Bm, c, 0, 0, 0); // hm
          c = __builtin_amdgcn_mfma_f32_16x16x32_f16(A[step][mt][0], Bh, c, 0, 0, 0); // hh
          accf[mt][nt] = c;
        }
      }

    // fold into running argmin (strict < + ascending t => earliest index)
#pragma unroll
    for (int nt = 0; nt < 2; ++nt) {
      float ev = e2r[t * 2 + nt];
      int col = t * 128 + wcol + nt * 16 + l16;
#pragma unroll
      for (int mt = 0; mt < 4; ++mt)
#pragma unroll
        for (int r = 0; r < 4; ++r) {
          float s = fmaf(-2.0f, accf[mt][nt][r], ev);
          int slot = mt * 4 + r;
          if (s < best[slot]) { best[slot] = s; bidx[slot] = col; }
        }
    }
    __syncthreads();        // esc readers done; next-tile loads + OH stores drained
  }

  // ---- cross-lane reduction: 64 rows x 64 slots; scratch over es region ----
  float* redm = (float*)U;                  // [64][64]
  int*   redi = (int*)(U + 16384);          // [64][64]
#pragma unroll
  for (int mt = 0; mt < 4; ++mt)
#pragma unroll
    for (int r = 0; r < 4; ++r) {
      int row = mt * 16 + quad * 4 + r;     // C-layout: row = quad*4 + reg
      redm[row * 64 + wid * 16 + l16] = best[mt * 4 + r];
      redi[row * 64 + wid * 16 + l16] = bidx[mt * 4 + r];
    }
  __syncthreads();
  int* cidx = (int*)(U + 65536);            // Zs region (dead)
  if (tid < 64) {
    float m = redm[tid * 64]; int mi = redi[tid * 64];
    for (int s = 1; s < 64; ++s) {
      float v = redm[tid * 64 + s]; int vi = redi[tid * 64 + s];
      if (v < m || (v == m && vi < mi)) { m = v; mi = vi; }
    }
    cidx[tid] = mi;
  }
  __syncthreads();          // cidx visible; all OH zero-stores long drained

  if (tid < 64) outOH[(size_t)(row0 + tid) * K_CB + cidx[tid]] = 1.0f;

  // quantized gather (emb L2-hot); NT stores keep L2 for epl/Z
#pragma unroll
  for (int i = 0; i < 8; ++i) {
    int idx = tid + 256 * i;
    int r = idx >> 5, c = (idx & 31) * 4;
    f32x4 v = *(const f32x4*)(emb + (size_t)cidx[r] * D_IN + c);
    __builtin_nontemporal_store(v, (f32x4*)(outQ + (size_t)(row0 + r) * D_IN + c));
  }
}

extern "C" void kernel_launch(void* const* d_in, const int* in_sizes, int n_in,
                              void* d_out, int out_size, void* d_ws, size_t ws_size,
                              hipStream_t stream) {
  (void)in_sizes; (void)n_in; (void)out_size; (void)ws_size;
  const float* Z   = (const float*)d_in[0];
  const float* W   = (const float*)d_in[1];
  const float* b   = (const float*)d_in[2];
  const float* emb = (const float*)d_in[3];
  float* outQ  = (float*)d_out;
  float* outOH = (float*)d_out + (size_t)N_ROWS * D_IN;

  // ws layout (bytes): epl 524288 | e2 8192   (total 532480)
  char* wsb = (char*)d_ws;
  _Float16* epl = (_Float16*)wsb;
  float*    e2  = (float*)(wsb + 524288);

  k_prep<<<128, 256, 0, stream>>>(emb, W, b, epl, e2);
  k_main<<<1024, 256, 0, stream>>>(Z, W, b, epl, e2, emb, outQ, outOH);
}

// Round 5
// 676.410 us; speedup vs baseline: 1.1639x; 1.1639x over previous
//
#include <hip/hip_runtime.h>
#include <float.h>

#define N_ROWS 65536
#define D_IN   128
#define DH     64
#define K_CB   2048

typedef const __attribute__((address_space(1))) void* gas_p;
typedef __attribute__((address_space(3))) void* las_p;
typedef _Float16 f16x8 __attribute__((ext_vector_type(8)));
typedef float    f32x4 __attribute__((ext_vector_type(4)));

// ---------------- K1: project 128 -> 64, emit 2-plane fp16 split -----------
// z_ = h + m (11+11 mantissa-bit split, error ~2^-22 |v|); rows stored [n][64]
// with a 16B-chunk XOR swizzle: chunk c stored at c ^ (n&7) (bank-conflict-free
// MFMA frag reads after a LINEAR global_load_lds copy).
// blocks 0..4095: z rows (16/block) + zero the matching one_hot rows (128 KB,
// nontemporal, overlapped with compute); blocks 4096..4223: embedding rows + e2.
__global__ __launch_bounds__(256) void k_project(
    const float* __restrict__ Z, const float* __restrict__ emb,
    const float* __restrict__ W, const float* __restrict__ b,
    _Float16* __restrict__ zpl,   // [2][N_ROWS][64]
    _Float16* __restrict__ epl,   // [2][K_CB][64]
    float* __restrict__ e2,
    float* __restrict__ outOH) {  // non-null => zero one_hot rows here
  __shared__ __align__(16) float Wl[64 * 140];   // stride 140: limits read conflicts
  __shared__ __align__(16) float Zl[16 * 128];
  int tid = threadIdx.x;
  const float* src; _Float16* dst; int n0; bool do_e2; size_t plane;
  if ((int)blockIdx.x < 4096) {
    src = Z;   dst = zpl; n0 = blockIdx.x * 16;          do_e2 = false; plane = (size_t)N_ROWS * 64;
  } else {
    src = emb; dst = epl; n0 = (blockIdx.x - 4096) * 16; do_e2 = true;  plane = (size_t)K_CB * 64;
  }

#pragma unroll
  for (int i = 0; i < 8; ++i) {
    int idx4 = tid + 256 * i;            // 0..2047 float4s
    int j = idx4 >> 5;
    int d4 = (idx4 & 31) * 4;
    *(float4*)&Wl[j * 140 + d4] = *(const float4*)(W + j * 128 + d4);
  }
#pragma unroll
  for (int i = 0; i < 2; ++i) {
    int idx4 = tid + 256 * i;            // 0..511 float4s
    int r = idx4 >> 5;
    int d4 = (idx4 & 31) * 4;
    *(float4*)&Zl[r * 128 + d4] = *(const float4*)(src + (size_t)(n0 + r) * 128 + d4);
  }
  int j = tid & 63, g = tid >> 6;        // j = output dim, g = wave -> 4 rows
  float bj = b[j];
  __syncthreads();

  // one_hot zeroing AFTER the barrier: streams under the FMA loop, drains only
  // at kernel end (no barrier waits on these store acks).
  if (outOH && (int)blockIdx.x < 4096) {
    f32x4 zz4 = (f32x4){0.f, 0.f, 0.f, 0.f};
    f32x4* dz = (f32x4*)(outOH + (size_t)n0 * K_CB);   // 16 rows x 2048 = 8192 float4
#pragma unroll
    for (int i = 0; i < 32; ++i)
      __builtin_nontemporal_store(zz4, dz + tid + 256 * i);
  }

  float acc[4] = {0.f, 0.f, 0.f, 0.f};
  for (int d4 = 0; d4 < 128; d4 += 4) {
    float4 w4 = *(float4*)&Wl[j * 140 + d4];
#pragma unroll
    for (int i = 0; i < 4; ++i) {
      float4 z4 = *(float4*)&Zl[(g * 4 + i) * 128 + d4]; // wave-uniform broadcast
      acc[i] = fmaf(z4.x, w4.x, fmaf(z4.y, w4.y, fmaf(z4.z, w4.z, fmaf(z4.w, w4.w, acc[i]))));
    }
  }
#pragma unroll
  for (int i = 0; i < 4; ++i) {
    int n = n0 + g * 4 + i;
    float v = acc[i] + bj;
    _Float16 h = (_Float16)v;  float rm = v - (float)h;
    _Float16 m = (_Float16)rm;
    int pos = (((j >> 3) ^ (n & 7)) << 3) | (j & 7);   // 16B-chunk swizzle
    size_t base = (size_t)n * 64 + pos;
    dst[base]         = h;
    dst[plane + base] = m;
    if (do_e2) {
      float s = v * v;                   // exact fp32 ||e_||^2
#pragma unroll
      for (int off = 32; off > 0; off >>= 1) s += __shfl_xor(s, off, 64);
      if (j == 0) e2[n] = s;
    }
  }
}

// ---------------- K2: MFMA score + argmin + fused epilogue -----------------
// 64 z-rows/block. 32 K-tiles of 64 cols, double-buffered Es, ONE barrier per
// tile (stage t+1 issued BEFORE compute of t -> L2 latency hides under MFMA).
// A-fragments hoisted to registers once (invariant across K). Wave w covers
// cols w*16..w*16+16 of each tile. 4 fp16 MFMA passes = fp32-accurate dots.
// LDS: Zs 16K (dead after hoist) + es0 16K + es1 16K = 48KB -> 3 blocks/CU.
__global__ __launch_bounds__(256, 3) void k_score(
    const _Float16* __restrict__ zpl,  // [2][N_ROWS][64] swizzled
    const _Float16* __restrict__ epl,  // [2][K_CB][64] swizzled
    const float* __restrict__ e2,      // [2048]
    const float* __restrict__ emb,     // [2048][128]
    float* __restrict__ outQ,
    float* __restrict__ outOH,         // null => fallback (write cidx_g)
    int* __restrict__ cidx_g) {
  __shared__ __align__(16) char U[49152];
  _Float16* Zs  = (_Float16*)U;             // [2][64][64] 16KB
  char*     es0 = U + 16384;                // [2][64][64] fp16, 16KB
  char*     es1 = U + 32768;                // 16KB

  int tid = threadIdx.x, lane = tid & 63, wid = tid >> 6;
  int quad = lane >> 4, l16 = lane & 15;
  int row0 = blockIdx.x * 64;

  // stage Z tile (2 planes x 8KB) + K-tile 0 -> es0 (2 planes x 8KB)
  for (int q = wid; q < 16; q += 4) {
    int p = q >> 3, within = (q & 7) * 1024;
    const char* g = (const char*)zpl + (size_t)p * ((size_t)N_ROWS * 128)
                  + (size_t)row0 * 128 + within + lane * 16;
    __builtin_amdgcn_global_load_lds((gas_p)g, (las_p)((char*)Zs + p * 8192 + within), 16, 0, 0);
  }
  for (int q = wid; q < 16; q += 4) {
    int p = q >> 3, within = (q & 7) * 1024;
    const char* g = (const char*)epl + (size_t)p * (K_CB * 128) + within + lane * 16;
    __builtin_amdgcn_global_load_lds((gas_p)g, (las_p)(es0 + p * 8192 + within), 16, 0, 0);
  }

  __syncthreads();                     // Zs + tile0 ready

  // ---- A-fragments to registers, once (invariant across all K-tiles) ----
  f16x8 A[2][4][2];
#pragma unroll
  for (int step = 0; step < 2; ++step)
#pragma unroll
    for (int mt = 0; mt < 4; ++mt) {
      int tr = mt * 16 + l16;
      int cph = (step * 4 + quad) ^ (tr & 7);
      const _Float16* pa = Zs + tr * 64 + cph * 8;
      A[step][mt][0] = *(const f16x8*)pa;          // hi
      A[step][mt][1] = *(const f16x8*)(pa + 4096); // mid
    }

  float best[16]; int bidx[16];
#pragma unroll
  for (int s = 0; s < 16; ++s) { best[s] = FLT_MAX; bidx[s] = 0; }

  // ---- 2-phase pipelined tile loop: 32 tiles x 64 cols, 1 barrier/tile ----
  for (int t = 0; t < 32; ++t) {
    const _Float16* esc = (const _Float16*)((t & 1) ? es1 : es0);
    if (t < 31) {                      // stage t+1 FIRST (latency under compute)
      char* esn = (t & 1) ? es0 : es1;
      for (int q = wid; q < 16; q += 4) {
        int p = q >> 3, within = (q & 7) * 1024;
        const char* g = (const char*)epl + (size_t)p * (K_CB * 128)
                      + (size_t)(t + 1) * 8192 + within + lane * 16;
        __builtin_amdgcn_global_load_lds((gas_p)g, (las_p)(esn + p * 8192 + within), 16, 0, 0);
      }
    }
    int col = t * 64 + wid * 16 + l16;
    float ev = e2[col];                // L2-hot; latency hidden under MFMA

    f32x4 accf[4];
#pragma unroll
    for (int mt = 0; mt < 4; ++mt) accf[mt] = (f32x4){0.f, 0.f, 0.f, 0.f};

#pragma unroll
    for (int step = 0; step < 2; ++step) {
      int tc = wid * 16 + l16;
      int cph = (step * 4 + quad) ^ (l16 & 7);
      const _Float16* pb = esc + tc * 64 + cph * 8;
      f16x8 Bh = *(const f16x8*)pb;
      f16x8 Bm = *(const f16x8*)(pb + 4096);
#pragma unroll
      for (int mt = 0; mt < 4; ++mt) {
        f32x4 c = accf[mt];
        c = __builtin_amdgcn_mfma_f32_16x16x32_f16(A[step][mt][1], Bm, c, 0, 0, 0); // mm
        c = __builtin_amdgcn_mfma_f32_16x16x32_f16(A[step][mt][1], Bh, c, 0, 0, 0); // mh
        c = __builtin_amdgcn_mfma_f32_16x16x32_f16(A[step][mt][0], Bm, c, 0, 0, 0); // hm
        c = __builtin_amdgcn_mfma_f32_16x16x32_f16(A[step][mt][0], Bh, c, 0, 0, 0); // hh
        accf[mt] = c;
      }
    }

    // fold into running argmin (strict < + ascending t => earliest index)
#pragma unroll
    for (int mt = 0; mt < 4; ++mt)
#pragma unroll
      for (int r = 0; r < 4; ++r) {
        float s = fmaf(-2.0f, accf[mt][r], ev);
        int slot = mt * 4 + r;
        if (s < best[slot]) { best[slot] = s; bidx[slot] = col; }
      }

    __syncthreads();   // esc readers done; t+1 loads drained (vmcnt0) -> ready
  }

  // ---- cross-lane reduction: 64 rows x 64 (wave,l16) slots; reuse U ----
  float* redm = (float*)U;                  // [64][64] 16KB (Zs dead)
  int*   redi = (int*)(U + 16384);          // [64][64] 16KB (es0 dead)
#pragma unroll
  for (int mt = 0; mt < 4; ++mt)
#pragma unroll
    for (int r = 0; r < 4; ++r) {
      int row = mt * 16 + quad * 4 + r;     // C-layout: row = quad*4 + reg
      redm[row * 64 + wid * 16 + l16] = best[mt * 4 + r];
      redi[row * 64 + wid * 16 + l16] = bidx[mt * 4 + r];
    }
  __syncthreads();
  int* cidx = (int*)(U + 32768);            // es1 dead
  if (tid < 64) {
    float m = redm[tid * 64]; int mi = redi[tid * 64];
    for (int s = 1; s < 64; ++s) {
      float v = redm[tid * 64 + s]; int vi = redi[tid * 64 + s];
      if (v < m || (v == m && vi < mi)) { m = v; mi = vi; }
    }
    cidx[tid] = mi;
  }
  __syncthreads();

  if (outOH) {
    // zeros were written by k_project (prior kernel on this stream => visible)
    if (tid < 64) outOH[(size_t)(row0 + tid) * K_CB + cidx[tid]] = 1.0f;
  } else {
    if (tid < 64) cidx_g[row0 + tid] = cidx[tid];
  }

  // quantized gather (emb L2-hot); NT stores keep L2 for epl/zpl
#pragma unroll
  for (int i = 0; i < 8; ++i) {
    int idx = tid + 256 * i;           // 0..2047 float4s
    int r = idx >> 5, c = (idx & 31) * 4;
    f32x4 v = *(const f32x4*)(emb + (size_t)cidx[r] * D_IN + c);
    __builtin_nontemporal_store(v, (f32x4*)(outQ + (size_t)(row0 + r) * D_IN + c));
  }
}

// ---------------- K3: fallback epilogue (zero one_hot + scatter) -----------
__global__ void k_epilogue(const int* __restrict__ cidx_g, float* __restrict__ outOH) {
  int tid  = threadIdx.x;
  int row0 = blockIdx.x * 64;
  float4 zz4 = make_float4(0.f, 0.f, 0.f, 0.f);
  for (int r = 0; r < 64; ++r) {
    float4* dst = (float4*)(outOH + (size_t)(row0 + r) * K_CB);
    dst[tid]       = zz4;
    dst[tid + 256] = zz4;
  }
  __syncthreads();
  if (tid < 64) {
    int r = row0 + tid;
    outOH[(size_t)r * K_CB + cidx_g[r]] = 1.0f;
  }
}

extern "C" void kernel_launch(void* const* d_in, const int* in_sizes, int n_in,
                              void* d_out, int out_size, void* d_ws, size_t ws_size,
                              hipStream_t stream) {
  (void)in_sizes; (void)n_in; (void)out_size;
  const float* Z   = (const float*)d_in[0];
  const float* W   = (const float*)d_in[1];
  const float* b   = (const float*)d_in[2];
  const float* emb = (const float*)d_in[3];
  float* outQ  = (float*)d_out;
  float* outOH = (float*)d_out + (size_t)N_ROWS * D_IN;

  // ws layout (bytes): epl 524288 | e2 8192 | (zpl 16777216  OR  cidx 262144)
  char* wsb = (char*)d_ws;
  _Float16* epl = (_Float16*)wsb;
  float*    e2  = (float*)(wsb + 524288);
  const size_t need_primary = 524288 + 8192 + (size_t)2 * N_ROWS * 64 * 2;

  if (ws_size >= need_primary) {
    _Float16* zpl = (_Float16*)(wsb + 532480);
    k_project<<<4224, 256, 0, stream>>>(Z, emb, W, b, zpl, epl, e2, outOH);
    k_score<<<1024, 256, 0, stream>>>(zpl, epl, e2, emb, outQ, outOH, nullptr);
  } else {
    // fallback: z planes live in the (not-yet-needed) one_hot region;
    // k_project must NOT zero it (aliases zpl) -> k_epilogue zeroes later.
    int*      cidx_g = (int*)(wsb + 532480);
    _Float16* zpl    = (_Float16*)outOH;
    k_project<<<4224, 256, 0, stream>>>(Z, emb, W, b, zpl, epl, e2, nullptr);
    k_score<<<1024, 256, 0, stream>>>(zpl, epl, e2, emb, outQ, nullptr, cidx_g);
    k_epilogue<<<1024, 256, 0, stream>>>(cidx_g, outOH);
  }
}